// Round 10
// baseline (180.348 us; speedup 1.0000x reference)
//
#include <hip/hip_runtime.h>
#include <math.h>

#define BB 256
#define L 512
#define NSIG 50

// composite-weight workspace layout (floats), after D region
#define D_FLOATS (256 * 4 * 512)
#define OFF_W12  0
#define OFF_B12  (50 * 176)
#define OFF_W34  (OFF_B12 + 200)
#define OFF_B34  (OFF_W34 + 50 * 52)
#define OFF_C12  (OFF_B34 + 50)
#define OFF_C34  (OFF_C12 + 50 * 448)   // total 45250 floats ~ 181 KB

__device__ __forceinline__ int refl(int i) {
    if (i < 0) i = -i;
    if (i >= L) i = 2 * L - 2 - i;
    return i;
}

__device__ __forceinline__ float selu(float x) {
    const float scale = 1.0507009873554804934193349852946f;
    const float alpha = 1.6732632423543772848170429916717f;
    return x > 0.f ? scale * x : scale * alpha * (__expf(x) - 1.f);
}

// ---------------- Kernel A: sharedCNN x2 + residual + LayerNorm ----------------
__global__ __launch_bounds__(256) void shared_ln_kernel(
    const float* __restrict__ latent,   // (B, 2048)
    const float* __restrict__ w1, const float* __restrict__ b1,   // (8,4,5),(8,)
    const float* __restrict__ w2, const float* __restrict__ b2,   // (4,8,5),(4,)
    const float* __restrict__ g,  const float* __restrict__ beta, // (512,),(512,)
    float* __restrict__ D)              // (B,4,512)
{
    __shared__ float xb[4][L];
    __shared__ float hb[8][L];
    __shared__ float yb[4][L];
    __shared__ float sw1[160], sb1[8], sw2[160], sb2[4];

    const int b = blockIdx.x;
    const int t = threadIdx.x;

    for (int i = t; i < 160; i += 256) { sw1[i] = w1[i]; sw2[i] = w2[i]; }
    if (t < 8) sb1[t] = b1[t];
    if (t < 4) sb2[t] = b2[t];

    const float* lp = latent + (size_t)b * 2048;
    for (int i = t; i < 2048; i += 256)
        xb[i & 3][i >> 2] = lp[i];
    __syncthreads();

    for (int pass = 0; pass < 2; ++pass) {
        const float (*src)[L] = (pass == 0) ? (const float (*)[L])xb
                                            : (const float (*)[L])yb;
        for (int idx = t; idx < 8 * L; idx += 256) {
            int co = idx >> 9, l = idx & (L - 1);
            float acc = sb1[co];
            #pragma unroll
            for (int ci = 0; ci < 4; ++ci) {
                const float* w = &sw1[(co * 4 + ci) * 5];
                #pragma unroll
                for (int k = 0; k < 5; ++k)
                    acc += w[k] * src[ci][refl(l + k - 2)];
            }
            hb[co][l] = selu(acc);
        }
        __syncthreads();
        for (int idx = t; idx < 4 * L; idx += 256) {
            int co = idx >> 9, l = idx & (L - 1);
            float acc = sb2[co];
            #pragma unroll
            for (int ci = 0; ci < 8; ++ci) {
                const float* w = &sw2[(co * 8 + ci) * 5];
                #pragma unroll
                for (int k = 0; k < 5; ++k)
                    acc += w[k] * hb[ci][refl(l + 2 * k - 4)];
            }
            if (pass == 1) acc += xb[co][l];
            yb[co][l] = acc;
        }
        __syncthreads();
    }

    const int wave = t >> 6;
    const int lane = t & 63;
    float v[8];
    float s = 0.f;
    #pragma unroll
    for (int j = 0; j < 8; ++j) { v[j] = yb[wave][lane * 8 + j]; s += v[j]; }
    #pragma unroll
    for (int off = 32; off > 0; off >>= 1) s += __shfl_down(s, off);
    s = __shfl(s, 0);
    const float mu = s * (1.f / 512.f);
    float s2 = 0.f;
    #pragma unroll
    for (int j = 0; j < 8; ++j) { float d = v[j] - mu; s2 += d * d; }
    #pragma unroll
    for (int off = 32; off > 0; off >>= 1) s2 += __shfl_down(s2, off);
    s2 = __shfl(s2, 0);
    const float rinv = rsqrtf(s2 * (1.f / 512.f) + 1e-10f);

    float* Dp = D + ((size_t)b * 4 + wave) * L;
    #pragma unroll
    for (int j = 0; j < 8; ++j) {
        int l = lane * 8 + j;
        Dp[l] = (v[j] - mu) * rinv * g[l] + beta[l];
    }
}

// ---------------- compose_kernel: build composite weights + edge corrections --
// conv12 = conv2 o conv1 (both linear, no activation between): 4->4, 11 taps.
// conv34 = conv4 o conv3: 4->1, 13 taps (conv4 dilated by 2).
// Edge corrections (reflect of the INTERMEDIATE differs from composite-on-
// reflected-input) computed by basis evaluation; hi edge = lo edge with
// kernels reversed (mirror symmetry of reflect padding).
__global__ __launch_bounds__(128) void compose_kernel(
    const float* __restrict__ w1, const float* __restrict__ b1,
    const float* __restrict__ w2, const float* __restrict__ b2,
    const float* __restrict__ w3, const float* __restrict__ b3,
    const float* __restrict__ w4, const float* __restrict__ b4,
    float* __restrict__ CW)
{
    const int s = blockIdx.x, t = threadIdx.x;
    __shared__ float W1[224], W2[160], W3[40], W4[10], B1[8], B2[4], B3[2], B4v[1];
    __shared__ float W12[176], W34[52];
    for (int i = t; i < 224; i += 128) W1[i] = w1[s * 224 + i];
    for (int i = t; i < 160; i += 128) W2[i] = w2[s * 160 + i];
    if (t < 40) W3[t] = w3[s * 40 + t];
    if (t < 10) W4[t] = w4[s * 10 + t];
    if (t < 8)  B1[t] = b1[s * 8 + t];
    if (t < 4)  B2[t] = b2[s * 4 + t];
    if (t < 2)  B3[t] = b3[s * 2 + t];
    if (t == 0) B4v[0] = b4[s];
    __syncthreads();

    // W12[o][i][tau], tau in [0,10]: sum_{m,j} w2[o,m,j] * w1[m,i,tau-j]
    for (int idx = t; idx < 176; idx += 128) {
        int o = idx / 44, r = idx % 44, i = r / 11, tau = r % 11;
        float v = 0.f;
        for (int m = 0; m < 8; ++m)
            for (int j = 0; j < 5; ++j) {
                int tt = tau - j;
                if (tt >= 0 && tt < 7)
                    v += W2[(o * 8 + m) * 5 + j] * W1[(m * 4 + i) * 7 + tt];
            }
        W12[idx] = v;
        CW[OFF_W12 + s * 176 + idx] = v;
    }
    // W34[i][tau], tau in [0,12]: sum_{m,k} w4[m,k] * w3[m,i,tau-2k]
    if (t < 52) {
        int i = t / 13, tau = t % 13;
        float v = 0.f;
        for (int m = 0; m < 2; ++m)
            for (int k = 0; k < 5; ++k) {
                int tt = tau - 2 * k;
                if (tt >= 0 && tt < 5)
                    v += W4[m * 5 + k] * W3[(m * 4 + i) * 5 + tt];
            }
        W34[t] = v;
        CW[OFF_W34 + s * 52 + t] = v;
    }
    if (t >= 52 && t < 56) {   // B12[o] = b2[o] + sum_m (sum_j w2) * b1[m]
        int o = t - 52;
        float v = B2[o];
        for (int m = 0; m < 8; ++m) {
            float sj = 0.f;
            for (int j = 0; j < 5; ++j) sj += W2[(o * 8 + m) * 5 + j];
            v += sj * B1[m];
        }
        CW[OFF_B12 + s * 4 + o] = v;
    }
    if (t == 56) {             // B34 = b4 + sum_m (sum_k w4) * b3[m]
        float v = B4v[0];
        for (int m = 0; m < 2; ++m) {
            float sk = 0.f;
            for (int k = 0; k < 5; ++k) sk += W4[m * 5 + k];
            v += sk * B3[m];
        }
        CW[OFF_B34 + s] = v;
    }
    __syncthreads();

    // C12[side][p][o][i][u]: true(conv2(reflect(conv1))) - composite, as linear
    // coeffs over d[i, u] (side 0) / d[i, 511-u] (side 1), p = edge offset.
    for (int idx = t; idx < 448; idx += 128) {
        int side = idx / 224, r = idx % 224;
        int p = r / 112, o = (r % 112) / 28, i = (r % 28) / 7, u = r % 7;
        float tru = 0.f;
        for (int m = 0; m < 8; ++m)
            for (int j = 0; j < 5; ++j) {
                int q = p + j - 2; int qr = q < 0 ? -q : q;   // reflect h1 index
                float h1v = 0.f;
                for (int tt = 0; tt < 7; ++tt) {
                    int v = qr + tt - 3; int a = v < 0 ? -v : v;  // reflect d
                    if (a == u) h1v += W1[(m * 4 + i) * 7 + (side ? 6 - tt : tt)];
                }
                tru += W2[(o * 8 + m) * 5 + (side ? 4 - j : j)] * h1v;
            }
        float virt = 0.f;
        for (int tau = 0; tau < 11; ++tau) {
            int v = p + tau - 5; int a = v < 0 ? -v : v;
            if (a == u) virt += W12[o * 44 + i * 11 + (side ? 10 - tau : tau)];
        }
        CW[OFF_C12 + s * 448 + idx] = tru - virt;
    }
    // C34[side][p][i][u]: coeffs over h2[i, u] / h2[i, 511-u], p in [0,3]
    for (int idx = t; idx < 224; idx += 128) {
        int side = idx / 112, r = idx % 112;
        int p = r / 28, i = (r % 28) / 7, u = r % 7;
        float tru = 0.f;
        for (int m = 0; m < 2; ++m)
            for (int k = 0; k < 5; ++k) {
                int v = p + 2 * k - 4; int vr = v < 0 ? -v : v;  // reflect h3
                float h3v = 0.f;
                for (int tt = 0; tt < 5; ++tt) {
                    int x = vr + tt - 2; int a = x < 0 ? -x : x; // reflect h2
                    if (a == u) h3v += W3[(m * 4 + i) * 5 + (side ? 4 - tt : tt)];
                }
                tru += W4[m * 5 + (side ? 4 - k : k)] * h3v;
            }
        float virt = 0.f;
        for (int tau = 0; tau < 13; ++tau) {
            int v = p + tau - 6; int a = v < 0 ? -v : v;
            if (a == u) virt += W34[i * 13 + (side ? 12 - tau : tau)];
        }
        CW[OFF_C34 + s * 224 + idx] = tru - virt;
    }
}

// ---------------- Kernel B: composed per-signal stack (2 conv phases) --------
// 256 thr, P=2 (p0=2t). Phase 1: conv12 (4->4, 11 taps, pad 5) + selu.
// Phase 2: conv34 (4->1, 13 taps, pad 6) + selu. Edge corrections applied by
// 4 edge threads from LDS scratch filled by spare threads. 4 barriers.
__global__ __launch_bounds__(256) void signal_kernel(
    const float* __restrict__ D, const float* __restrict__ CW,
    float* __restrict__ out)
{
    const int s = blockIdx.x;
    const int b = blockIdx.y;
    const int t = threadIdx.x;
    const int p0 = t * 2;

    __shared__ float dB[4][528];    // pad 8, d_r[-5..516] at idx 3..524
    __shared__ float h2B[4][524];   // pad 6, h2_r[-6..517] at idx 0..523
    __shared__ float sD12[2][2][4];
    __shared__ float sD34[2][4];

    const float* W12 = CW + OFF_W12 + s * 176;
    const float* B12 = CW + OFF_B12 + s * 4;
    const float* W34 = CW + OFF_W34 + s * 52;
    const float* B34 = CW + OFF_B34 + s;
    const float* C12 = CW + OFF_C12 + s * 448;
    const float* C34 = CW + OFF_C34 + s * 224;

    // ---- stage D with fused reflect halo (width 5) ----
    {
        const float4* Dv = (const float4*)(D + (size_t)b * 2048);
        #pragma unroll
        for (int j = 0; j < 2; ++j) {
            int i = t + j * 256;
            float4 v = Dv[i];
            int c = i >> 7, cc = i & 127, col = cc << 2;
            *(float4*)&dB[c][8 + col] = v;
            if (cc == 0)   { dB[c][7] = v.y; dB[c][6] = v.z; dB[c][5] = v.w; }
            if (cc == 1)   { dB[c][4] = v.x; dB[c][3] = v.y; }
            if (cc == 127) { dB[c][520] = v.z; dB[c][521] = v.y; dB[c][522] = v.x; }
            if (cc == 126) { dB[c][523] = v.w; dB[c][524] = v.z; }
        }
    }
    __syncthreads();   // B1

    // ---- conv12 FMA (all threads) + Delta12 (threads 64..79) ----
    float acc[4][2];
    #pragma unroll
    for (int o = 0; o < 4; ++o) { float bb = B12[o]; acc[o][0] = bb; acc[o][1] = bb; }
    #pragma unroll
    for (int ci = 0; ci < 4; ++ci) {
        float x[12];                         // d_r[p0-5 .. p0+6]
        const float* row = &dB[ci][3 + p0];
        #pragma unroll
        for (int j = 0; j < 12; ++j) x[j] = row[j];
        #pragma unroll
        for (int o = 0; o < 4; ++o) {
            const float* w = &W12[o * 44 + ci * 11];
            #pragma unroll
            for (int tau = 0; tau < 11; ++tau) {
                float wv = w[tau];
                acc[o][0] += wv * x[tau];
                acc[o][1] += wv * x[tau + 1];
            }
        }
    }
    if (t >= 64 && t < 80) {
        int r = t - 64, side = r >> 3, p = (r >> 2) & 1, o = r & 3;
        const float* c = C12 + side * 224 + p * 112 + o * 28;
        float d = 0.f;
        #pragma unroll
        for (int i = 0; i < 4; ++i)
            #pragma unroll
            for (int u = 0; u < 7; ++u)
                d += c[i * 7 + u] * dB[i][side ? 8 + 511 - u : 8 + u];
        sD12[side][p][o] = d;
    }
    __syncthreads();   // B2

    if (t == 0) {
        #pragma unroll
        for (int o = 0; o < 4; ++o) { acc[o][0] += sD12[0][0][o]; acc[o][1] += sD12[0][1][o]; }
    }
    if (t == 255) {
        #pragma unroll
        for (int o = 0; o < 4; ++o) { acc[o][0] += sD12[1][1][o]; acc[o][1] += sD12[1][0][o]; }
    }
    #pragma unroll
    for (int o = 0; o < 4; ++o) {
        float e0 = selu(acc[o][0]), e1 = selu(acc[o][1]);
        float2 v = { e0, e1 };
        *(float2*)&h2B[o][6 + p0] = v;
        if (t == 0)   h2B[o][5] = e1;
        if (t == 1)   { h2B[o][4] = e0; h2B[o][3] = e1; }
        if (t == 2)   { h2B[o][2] = e0; h2B[o][1] = e1; }
        if (t == 3)   h2B[o][0] = e0;
        if (t == 255) h2B[o][518] = e0;
        if (t == 254) { h2B[o][519] = e1; h2B[o][520] = e0; }
        if (t == 253) { h2B[o][521] = e1; h2B[o][522] = e0; }
        if (t == 252) h2B[o][523] = e1;
    }
    __syncthreads();   // B3

    // ---- conv34 FMA (all threads) + Delta34 (threads 64..71) ----
    float a0 = *B34, a1 = a0;
    #pragma unroll
    for (int i = 0; i < 4; ++i) {
        float y[14];                         // h2_r[p0-6 .. p0+7]
        const float* row = &h2B[i][p0];
        #pragma unroll
        for (int j = 0; j < 14; ++j) y[j] = row[j];
        const float* w = &W34[i * 13];
        #pragma unroll
        for (int tau = 0; tau < 13; ++tau) {
            float wv = w[tau];
            a0 += wv * y[tau];
            a1 += wv * y[tau + 1];
        }
    }
    if (t >= 64 && t < 72) {
        int r = t - 64, side = r >> 2, p = r & 3;
        const float* c = C34 + side * 112 + p * 28;
        float d = 0.f;
        #pragma unroll
        for (int i = 0; i < 4; ++i)
            #pragma unroll
            for (int u = 0; u < 7; ++u)
                d += c[i * 7 + u] * h2B[i][side ? 6 + 511 - u : 6 + u];
        sD34[side][p] = d;
    }
    __syncthreads();   // B4

    if (t == 0)   { a0 += sD34[0][0]; a1 += sD34[0][1]; }
    if (t == 1)   { a0 += sD34[0][2]; a1 += sD34[0][3]; }
    if (t == 255) { a0 += sD34[1][1]; a1 += sD34[1][0]; }
    if (t == 254) { a0 += sD34[1][3]; a1 += sD34[1][2]; }
    float2 rv = { selu(a0), selu(a1) };
    *(float2*)&out[((size_t)b * NSIG + s) * L + p0] = rv;
}

extern "C" void kernel_launch(void* const* d_in, const int* in_sizes, int n_in,
                              void* d_out, int out_size, void* d_ws, size_t ws_size,
                              hipStream_t stream) {
    const float* latent = (const float*)d_in[0];
    const float* sw1 = (const float*)d_in[1];
    const float* sb1 = (const float*)d_in[2];
    const float* sw2 = (const float*)d_in[3];
    const float* sb2 = (const float*)d_in[4];
    const float* ln_g = (const float*)d_in[5];
    const float* ln_b = (const float*)d_in[6];
    const float* g_w1 = (const float*)d_in[7];
    const float* g_b1 = (const float*)d_in[8];
    const float* g_w2 = (const float*)d_in[9];
    const float* g_b2 = (const float*)d_in[10];
    const float* g_w3 = (const float*)d_in[11];
    const float* g_b3 = (const float*)d_in[12];
    const float* g_w4 = (const float*)d_in[13];
    const float* g_b4 = (const float*)d_in[14];
    float* out = (float*)d_out;
    float* D = (float*)d_ws;                   // (256,4,512) f32 = 2 MB
    float* CW = (float*)d_ws + D_FLOATS;       // composite weights ~181 KB

    compose_kernel<<<NSIG, 128, 0, stream>>>(g_w1, g_b1, g_w2, g_b2,
                                             g_w3, g_b3, g_w4, g_b4, CW);
    shared_ln_kernel<<<BB, 256, 0, stream>>>(latent, sw1, sb1, sw2, sb2,
                                             ln_g, ln_b, D);
    signal_kernel<<<dim3(NSIG, BB), 256, 0, stream>>>(D, CW, out);
}